// Round 13
// baseline (339.865 us; speedup 1.0000x reference)
//
#include <hip/hip_runtime.h>
#include <stdint.h>

typedef __attribute__((ext_vector_type(4))) float f32x4;
typedef __attribute__((ext_vector_type(8))) short bf16x8;
typedef __attribute__((ext_vector_type(4))) short bf16x4v;
typedef __attribute__((ext_vector_type(4))) unsigned int u32x4;

#define NBATCH 8
#define LQS    1024
#define LKS    4096
#define DDIM   1024
#define QKSCALE 0.03125f
#define NEGINF -1000000000.0f
#define BK 64

__device__ __forceinline__ short f2bf(float x) {  // round-to-nearest-even
    unsigned u = __builtin_bit_cast(unsigned, x);
    unsigned r = (u + 0x7fffu + ((u >> 16) & 1u)) >> 16;
    return (short)r;
}
__device__ __forceinline__ float bf2f(short s) {
    unsigned u = ((unsigned)(unsigned short)s) << 16;
    return __builtin_bit_cast(float, u);
}

__device__ __forceinline__ bf16x8 cvt8(const float* f) {
    const u32x4* u = (const u32x4*)f;
    const u32x4 a = u[0], b = u[1];
    union { unsigned w[4]; bf16x8 v; } c;
    c.w[0] = __builtin_amdgcn_perm(a[1], a[0], 0x07060302u);
    c.w[1] = __builtin_amdgcn_perm(a[3], a[2], 0x07060302u);
    c.w[2] = __builtin_amdgcn_perm(b[1], b[0], 0x07060302u);
    c.w[3] = __builtin_amdgcn_perm(b[3], b[2], 0x07060302u);
    return c.v;
}

__device__ __forceinline__ void g2l16(const void* g, void* lds) {
    __builtin_amdgcn_global_load_lds(
        (const __attribute__((address_space(1))) unsigned int*)g,
        (__attribute__((address_space(3))) unsigned int*)lds,
        16, 0, 0);
}

// bijective XCD swizzle (all grids % 8 == 0)
__device__ __forceinline__ int xcd_swz(int bid, int nwg) {
    return (bid & 7) * (nwg >> 3) + (bid >> 3);
}

// ---- mask dtype detection ----
__global__ void detect_kernel(const unsigned char* __restrict__ mb,
                              int* __restrict__ flags) {
    if (threadIdx.x != 0 || blockIdx.x != 0) return;
    int is_i32 = 1;
    for (int i = 0; i < 256; ++i) {
        if ((i & 3) != 0 && mb[i] != 0) { is_i32 = 0; break; }
    }
    flags[0] = is_i32;
}

// ---- bulk fp32 -> bf16 ----
__global__ __launch_bounds__(256) void cvt_kernel(
    const float* __restrict__ src, short* __restrict__ dst, int n8) {
    const int stride = gridDim.x * 256;
    for (int i = blockIdx.x * 256 + threadIdx.x; i < n8; i += stride)
        ((bf16x8*)dst)[i] = cvt8(src + (size_t)i * 8);
}

// ---- transpose V[k][d] fp32 -> VT[d][k] bf16, 64x64 tiles ----
__global__ __launch_bounds__(256) void transv_kernel(
    const float* __restrict__ V, short* __restrict__ VT) {
    __shared__ short LDSt[64 * 72];
    const int tid = threadIdx.x;
    const int cb  = blockIdx.x >> 10;
    const int t   = blockIdx.x & 1023;
    const int kt  = t >> 4, dt = t & 15;
    const int k0  = kt * 64, d0 = dt * 64;
    const float* Vb  = V  + (size_t)cb * LKS * DDIM;
    short*       VTb = VT + (size_t)cb * ((size_t)DDIM * LKS);

    const int r  = tid >> 4;
    const int cp = (tid & 15) * 4;
#pragma unroll
    for (int rr = 0; rr < 4; ++rr) {
        const int row = rr * 16 + r;
        const f32x4 v = *(const f32x4*)(Vb + (size_t)(k0 + row) * DDIM + d0 + cp);
#pragma unroll
        for (int i = 0; i < 4; ++i) LDSt[(cp + i) * 72 + row] = f2bf(v[i]);
    }
    __syncthreads();
    const int dr = tid >> 2;
    const int kq = (tid & 3) * 16;
    const bf16x8 o0 = *(const bf16x8*)&LDSt[dr * 72 + kq];
    const bf16x8 o1 = *(const bf16x8*)&LDSt[dr * 72 + kq + 8];
    short* dst = VTb + (size_t)(d0 + dr) * LKS + k0 + kq;
    *(bf16x8*)dst       = o0;
    *(bf16x8*)(dst + 8) = o1;
}

// ============ shared staging / fragment helpers ============
// 512-thread staging: 2 g2l16/thread per 128-row half
__device__ __forceinline__ void stage_half(const short* gbase, int ld,
                                           short* ldshalf, int tid) {
    const int r0 = tid >> 3;
    const int gc = (tid & 7) ^ (r0 & 7);
    const short* s0 = gbase + (size_t)r0 * ld + gc * 8;
    const short* s1 = gbase + (size_t)(r0 + 64) * ld + gc * 8;
    g2l16(s0, ldshalf + (tid & 0x1C0) * 8);
    g2l16(s1, ldshalf + 4096 + (tid & 0x1C0) * 8);
}

// 256-thread staging: 4 g2l16/thread per 128-row half (same swizzle convention)
__device__ __forceinline__ void stage_half_256(const short* gbase, int ld,
                                               short* ldshalf, int tid) {
#pragma unroll
    for (int p = 0; p < 4; ++p) {
        const int r0 = p * 32 + (tid >> 3);
        const int gc = (tid & 7) ^ (r0 & 7);
        g2l16(gbase + (size_t)r0 * ld + gc * 8,
              ldshalf + p * 2048 + (tid & 0xC0) * 8);
    }
}

__device__ __forceinline__ bf16x8 rdfrag(const short* lds, int base, int r, int c) {
    return *(const bf16x8*)&lds[base + r * 64 + ((c ^ (r & 7)) << 3)];
}

#define MFMA16(d, a, b) d = __builtin_amdgcn_mfma_f32_16x16x32_bf16(a, b, d, 0, 0, 0)

// MFMA order: all k-half-0 first, then k-half-1 -> dependent reuse of each acc at
// distance 8 (covers MFMA latency at 1 wave/SIMD); per-acc accumulation order is
// UNCHANGED vs previous rounds (a*b[0] then a*b[1]) -> numerics identical.
#define PHASE(MF0, STAGE, TAIL)                                             \
    {                                                                       \
        bf16x8 a00 = rdfrag(lds, aBase, (MF0) * 16 + lo, g);                \
        bf16x8 a01 = rdfrag(lds, aBase, (MF0) * 16 + lo, 4 + g);            \
        bf16x8 a10 = rdfrag(lds, aBase, (MF0) * 16 + 16 + lo, g);          \
        bf16x8 a11 = rdfrag(lds, aBase, (MF0) * 16 + 16 + lo, 4 + g);      \
        STAGE;                                                              \
        asm volatile("s_barrier" ::: "memory");                             \
        __builtin_amdgcn_s_setprio(1);                                      \
        _Pragma("unroll")                                                   \
        for (int nf = 0; nf < 4; ++nf) {                                    \
            MFMA16(acc[(MF0)][nf], a00, bfr[nf][0]);                        \
            MFMA16(acc[(MF0) + 1][nf], a10, bfr[nf][0]);                    \
        }                                                                   \
        _Pragma("unroll")                                                   \
        for (int nf = 0; nf < 4; ++nf) {                                    \
            MFMA16(acc[(MF0)][nf], a01, bfr[nf][1]);                        \
            MFMA16(acc[(MF0) + 1][nf], a11, bfr[nf][1]);                    \
        }                                                                   \
        __builtin_amdgcn_s_setprio(0);                                      \
        TAIL;                                                               \
        asm volatile("s_barrier" ::: "memory");                             \
    }

// Epilogue store: EPI 0 = fp32*scale ; 1 = bf16 ; 2 = fp32+bias ; 3 = bf16*scale

// ============ 256x256 4-PHASE GEMM-BT, 512 thr / 8 waves (proven) ============
template <int EPI>
__device__ __forceinline__ void gemm8p_body(
    const short* __restrict__ A, int lda,
    const short* __restrict__ B, int ldb,
    void* __restrict__ C, int ldc,
    const float* __restrict__ bias,
    int m0, int n0, int NK, float scale, short* lds) {

    const int tid = threadIdx.x;
    const int w = tid >> 6, lane = tid & 63;
    const int lo = lane & 15, g = lane >> 4;
    const int wr = w >> 2, wc = w & 3;

    const short* gA0 = A + (size_t)m0 * lda;
    const short* gA1 = A + (size_t)(m0 + 128) * lda;
    const short* gB0 = B + (size_t)n0 * ldb;
    const short* gB1 = B + (size_t)(n0 + 128) * ldb;

    f32x4 acc[8][4];
#pragma unroll
    for (int mf = 0; mf < 8; ++mf)
#pragma unroll
        for (int nf = 0; nf < 4; ++nf) acc[mf][nf] = (f32x4){0.f, 0.f, 0.f, 0.f};

    stage_half(gA0, lda, lds + 0,     tid);
    stage_half(gA1, lda, lds + 8192,  tid);
    stage_half(gB0, ldb, lds + 16384, tid);
    stage_half(gB1, ldb, lds + 24576, tid);
    stage_half(gB0 + BK, ldb, lds + 32768 + 16384, tid);
    stage_half(gB1 + BK, ldb, lds + 32768 + 24576, tid);
    asm volatile("s_waitcnt vmcnt(4)" ::: "memory");
    asm volatile("s_barrier" ::: "memory");

    for (int kt = 0; kt < NK; ++kt) {
        const int cb = (kt & 1) << 15;
        const int ob = cb ^ 32768;
        const int aBase = cb + wr * 8192;
        const int bBase = cb + 16384 + (wc >> 1) * 8192;
        const int brow  = (wc & 1) * 64;
        const int kA = (kt + 1) * BK, kB = (kt + 2) * BK;
        const bool doA = (kt + 1) < NK, doB = (kt + 2) < NK;

        bf16x8 bfr[4][2];
#pragma unroll
        for (int nf = 0; nf < 4; ++nf) {
            bfr[nf][0] = rdfrag(lds, bBase, brow + nf * 16 + lo, g);
            bfr[nf][1] = rdfrag(lds, bBase, brow + nf * 16 + lo, 4 + g);
        }
        PHASE(0, if (doA) stage_half(gA0 + kA, lda, lds + ob, tid), )
        PHASE(2, if (doA) stage_half(gA1 + kA, lda, lds + ob + 8192, tid), )
        PHASE(4, if (doB) stage_half(gB0 + kB, ldb, lds + cb + 16384, tid), )
        PHASE(6, if (doB) stage_half(gB1 + kB, ldb, lds + cb + 24576, tid),
                 {
                     if (doB) { asm volatile("s_waitcnt vmcnt(4)" ::: "memory"); }
                     else     { asm volatile("s_waitcnt vmcnt(0)" ::: "memory"); }
                 })
    }

    if constexpr (EPI == 0 || EPI == 2) {
#pragma unroll
        for (int nf = 0; nf < 4; ++nf) {
            const int col = n0 + wc * 64 + nf * 16 + lo;
            float bv = 0.f;
            if constexpr (EPI == 2) bv = bias[col];
#pragma unroll
            for (int mf = 0; mf < 8; ++mf) {
#pragma unroll
                for (int rr = 0; rr < 4; ++rr) {
                    const size_t oa =
                        (size_t)(m0 + wr * 128 + mf * 16 + g * 4 + rr) * ldc + col;
                    if constexpr (EPI == 0) ((float*)C)[oa] = acc[mf][nf][rr] * scale;
                    else                    ((float*)C)[oa] = acc[mf][nf][rr] + bv;
                }
            }
        }
    } else {
        // bf16: LDS-coalesced, two half-passes over m
        const float sc_ = (EPI == 3) ? scale : 1.f;
#pragma unroll
        for (int half = 0; half < 2; ++half) {
            if (wr == half) {
#pragma unroll
                for (int nf = 0; nf < 4; ++nf)
#pragma unroll
                    for (int mf = 0; mf < 8; ++mf)
#pragma unroll
                        for (int rr = 0; rr < 4; ++rr)
                            lds[(mf * 16 + g * 4 + rr) * 264 + wc * 64 + nf * 16 + lo] =
                                f2bf(acc[mf][nf][rr] * sc_);
            }
            __syncthreads();
#pragma unroll
            for (int it = 0; it < 8; ++it) {
                const int idx = it * 512 + tid;
                const int r_  = idx >> 5;
                const int c_  = (idx & 31) * 8;
                *(bf16x8*)((short*)C + (size_t)(m0 + half * 128 + r_) * ldc + n0 + c_) =
                    *(const bf16x8*)&lds[r_ * 264 + c_];
            }
            __syncthreads();
        }
    }
}

// ============ 256x128 4-PHASE, 256 thr / 4 waves (2M x 2N, 128x64/wave) ============
// LDS 96KiB: buf @ b*24576 shorts {A0 @0, A1 @8192, B @16384}.
// vmcnt accounting (4 ops per stage_half_256):
//  prologue: A0,A1,B(0),B(1) = 16 ops -> vmcnt(4) retires kt0's 12, leaves B(1).
//  steady kt: stages A0(kt+1),A1(kt+1),B(kt+2) = 12 atop 4 -> vmcnt(4) retires
//  [B(kt+1),A0(kt+1),A1(kt+1)] oldest-first, leaves B(kt+2).
//  kt==NK-2 (doB false): only 8 issued -> vmcnt(0) full drain (r10 invariant fix).
template <int EPI>
__device__ __forceinline__ void gemm4w_body(
    const short* __restrict__ A, int lda,
    const short* __restrict__ B, int ldb,
    void* __restrict__ C, int ldc,
    const float* __restrict__ bias,
    int m0, int n0, int NK, float scale, short* lds) {

    const int tid = threadIdx.x;
    const int w = tid >> 6, lane = tid & 63;
    const int lo = lane & 15, g = lane >> 4;
    const int wr = w >> 1, wc = w & 1;

    const short* gA0 = A + (size_t)m0 * lda;
    const short* gA1 = A + (size_t)(m0 + 128) * lda;
    const short* gB0 = B + (size_t)n0 * ldb;

    f32x4 acc[8][4];
#pragma unroll
    for (int mf = 0; mf < 8; ++mf)
#pragma unroll
        for (int nf = 0; nf < 4; ++nf) acc[mf][nf] = (f32x4){0.f, 0.f, 0.f, 0.f};

    stage_half_256(gA0, lda, lds + 0,     tid);
    stage_half_256(gA1, lda, lds + 8192,  tid);
    stage_half_256(gB0, ldb, lds + 16384, tid);
    stage_half_256(gB0 + BK, ldb, lds + 24576 + 16384, tid);
    asm volatile("s_waitcnt vmcnt(4)" ::: "memory");
    asm volatile("s_barrier" ::: "memory");

    for (int kt = 0; kt < NK; ++kt) {
        const int cbuf = (kt & 1) * 24576;
        const int obuf = cbuf ^ 24576;
        const int aBase = cbuf + wr * 8192;
        const int bBase = cbuf + 16384;
        const int brow  = wc * 64;
        const int kA = (kt + 1) * BK, kB = (kt + 2) * BK;
        const bool doA = (kt + 1) < NK, doB = (kt + 2) < NK;

        bf16x8 bfr[4][2];
#pragma unroll
        for (int nf = 0; nf < 4; ++nf) {
            bfr[nf][0] = rdfrag(lds, bBase, brow + nf * 16 + lo, g);
            bfr[nf][1] = rdfrag(lds, bBase, brow + nf * 16 + lo, 4 + g);
        }
        PHASE(0, if (doA) stage_half_256(gA0 + kA, lda, lds + obuf, tid), )
        PHASE(2, if (doA) stage_half_256(gA1 + kA, lda, lds + obuf + 8192, tid), )
        PHASE(4, if (doB) stage_half_256(gB0 + kB, ldb, lds + cbuf + 16384, tid), )
        PHASE(6, ,
                 {
                     if (doB) { asm volatile("s_waitcnt vmcnt(4)" ::: "memory"); }
                     else     { asm volatile("s_waitcnt vmcnt(0)" ::: "memory"); }
                 })
    }

    if constexpr (EPI == 0 || EPI == 2) {
#pragma unroll
        for (int nf = 0; nf < 4; ++nf) {
            const int col = n0 + wc * 64 + nf * 16 + lo;
            float bv = 0.f;
            if constexpr (EPI == 2) bv = bias[col];
#pragma unroll
            for (int mf = 0; mf < 8; ++mf) {
#pragma unroll
                for (int rr = 0; rr < 4; ++rr) {
                    const size_t oa =
                        (size_t)(m0 + wr * 128 + mf * 16 + g * 4 + rr) * ldc + col;
                    if constexpr (EPI == 0) ((float*)C)[oa] = acc[mf][nf][rr] * scale;
                    else                    ((float*)C)[oa] = acc[mf][nf][rr] + bv;
                }
            }
        }
    } else {
        // bf16: LDS-coalesced, two half-passes over m; tile half = [128][136]
        const float sc_ = (EPI == 3) ? scale : 1.f;
#pragma unroll
        for (int half = 0; half < 2; ++half) {
            if (wr == half) {
#pragma unroll
                for (int nf = 0; nf < 4; ++nf)
#pragma unroll
                    for (int mf = 0; mf < 8; ++mf)
#pragma unroll
                        for (int rr = 0; rr < 4; ++rr)
                            lds[(mf * 16 + g * 4 + rr) * 136 + wc * 64 + nf * 16 + lo] =
                                f2bf(acc[mf][nf][rr] * sc_);
            }
            __syncthreads();
#pragma unroll
            for (int it = 0; it < 8; ++it) {
                const int idx = it * 256 + tid;
                const int r_  = idx >> 4;
                const int c_  = (idx & 15) * 8;
                *(bf16x8*)((short*)C + (size_t)(m0 + half * 128 + r_) * ldc + n0 + c_) =
                    *(const bf16x8*)&lds[r_ * 136 + c_];
            }
            __syncthreads();
        }
    }
}

// ---- gemm1: S[q][k] = bf16(scale * Qb·Kb^T) ; 256x256 tiles, grid nb*64 ----
__global__ __launch_bounds__(512, 2) void gemm1_kernel(
    const short* __restrict__ Qb, const short* __restrict__ Kb,
    short* __restrict__ Sb) {
    __shared__ __align__(16) short lds[65536];
    const int bid = xcd_swz(blockIdx.x, gridDim.x);
    const int cb = bid >> 6;
    const int t  = bid & 63;
    gemm8p_body<3>(Qb + (size_t)cb * LQS * DDIM, DDIM,
                   Kb + (size_t)cb * LKS * DDIM, DDIM,
                   Sb + (size_t)cb * ((size_t)LQS * LKS), LKS, nullptr,
                   (t >> 4) * 256, (t & 15) * 256, DDIM / BK, QKSCALE, lds);
}

// ---- gemm2: attedT[d][q] = VT·P^T ; 256x128 tiles 4-wave, grid nb*32 ----
__global__ __launch_bounds__(256, 1) void gemm2_kernel(
    const short* __restrict__ VT, const short* __restrict__ Pd,
    short* __restrict__ attedT) {
    __shared__ __align__(16) short lds[49152];
    const int bid = xcd_swz(blockIdx.x, gridDim.x);
    const int cb = bid >> 5;
    const int t  = bid & 31;
    gemm4w_body<1>(VT + (size_t)cb * ((size_t)DDIM * LKS), LKS,
                   Pd + (size_t)cb * ((size_t)LQS * LKS), LKS,
                   attedT + (size_t)cb * ((size_t)DDIM * LQS), LQS, nullptr,
                   (t >> 3) * 256, (t & 7) * 128, LKS / BK, 1.f, lds);
}

// ---- merge: out[(b,d)][o] = attedT·Wb^T + bias ; 256x128 4-wave, grid nb*32 ----
__global__ __launch_bounds__(256, 1) void merge_kernel(
    const short* __restrict__ attedT, const short* __restrict__ Wb,
    const float* __restrict__ bias, float* __restrict__ out) {
    __shared__ __align__(16) short lds[49152];
    const int bid = xcd_swz(blockIdx.x, gridDim.x);
    const int mt = bid >> 3;
    const int nt = bid & 7;
    gemm4w_body<2>(attedT, DDIM, Wb, DDIM, out, DDIM, bias,
                   mt * 256, nt * 128, DDIM / BK, 1.f, lds);
}

// ---- softmax: one block per q-row; reads bf16 S, writes DENSE P bf16 ----
__global__ __launch_bounds__(256) void softmax_kernel(
    const short* __restrict__ Sb, short* __restrict__ Pd,
    const void* __restrict__ mask, const int* __restrict__ flags, int c0) {
    __shared__ float red[4];
    const int tid = threadIdx.x, w = tid >> 6, lane = tid & 63;
    const int cb = blockIdx.x >> 10;
    const int q  = blockIdx.x & 1023;
    const int mflag = flags[0];

    const short* Srow = Sb + ((size_t)cb * LQS + q) * LKS;
    const size_t roff = ((size_t)(c0 + cb) * LQS + q) * LKS;
    const size_t m4   = roff >> 2;   // int4 / uchar4 base index

    float sc[16];
#pragma unroll
    for (int j = 0; j < 2; ++j) {
        const int i8 = j * 256 + tid;
        const bf16x8 sv = ((const bf16x8*)Srow)[i8];
        int mm[8];
        if (mflag) {
            const int4 a = ((const int4*)mask)[m4 + 2 * i8];
            const int4 b = ((const int4*)mask)[m4 + 2 * i8 + 1];
            mm[0] = a.x; mm[1] = a.y; mm[2] = a.z; mm[3] = a.w;
            mm[4] = b.x; mm[5] = b.y; mm[6] = b.z; mm[7] = b.w;
        } else {
            const uchar4 a = ((const uchar4*)mask)[m4 + 2 * i8];
            const uchar4 b = ((const uchar4*)mask)[m4 + 2 * i8 + 1];
            mm[0] = a.x; mm[1] = a.y; mm[2] = a.z; mm[3] = a.w;
            mm[4] = b.x; mm[5] = b.y; mm[6] = b.z; mm[7] = b.w;
        }
#pragma unroll
        for (int i = 0; i < 8; ++i)
            sc[j * 8 + i] = mm[i] ? NEGINF : bf2f(sv[i]);
    }

    float lm = -INFINITY;
#pragma unroll
    for (int i = 0; i < 16; ++i) lm = fmaxf(lm, sc[i]);
#pragma unroll
    for (int off = 1; off < 64; off <<= 1) lm = fmaxf(lm, __shfl_xor(lm, off));
    if (lane == 0) red[w] = lm;
    __syncthreads();
    const float m = fmaxf(fmaxf(red[0], red[1]), fmaxf(red[2], red[3]));

    float p[16], ls = 0.f;
#pragma unroll
    for (int i = 0; i < 16; ++i) { p[i] = __expf(sc[i] - m); ls += p[i]; }
#pragma unroll
    for (int off = 1; off < 64; off <<= 1) ls += __shfl_xor(ls, off);
    __syncthreads();
    if (lane == 0) red[w] = ls;
    __syncthreads();
    const float inv = 1.f / (red[0] + red[1] + red[2] + red[3]);

    short* Prow = Pd + ((size_t)cb * LQS + q) * LKS;
#pragma unroll
    for (int j = 0; j < 2; ++j) {
        bf16x8 pv;
#pragma unroll
        for (int i = 0; i < 8; ++i) pv[i] = f2bf(p[j * 8 + i] * inv);
        ((bf16x8*)Prow)[j * 256 + tid] = pv;
    }
}

extern "C" void kernel_launch(void* const* d_in, const int* in_sizes, int n_in,
                              void* d_out, int out_size, void* d_ws, size_t ws_size,
                              hipStream_t stream) {
    // setup_inputs order: v, k, q, mask, W_merge, b_merge (fp32; mask i32/u8)
    const float* v    = (const float*)d_in[0];
    const float* k    = (const float*)d_in[1];
    const float* q    = (const float*)d_in[2];
    const void*  mask = d_in[3];
    const float* Wm   = (const float*)d_in[4];
    const float* bias = (const float*)d_in[5];
    float* out = (float*)d_out;

    const size_t base = 4096 + (2ull << 20);
    int nb = 0;
    for (int cand = 8; cand >= 1; cand >>= 1)
        if (base + (size_t)cand * (36ull << 20) <= ws_size) { nb = cand; break; }
    if (!nb) return;

    int*   flags = (int*)d_ws;
    short* Wb    = (short*)((char*)d_ws + 4096);
    char*  ar    = (char*)d_ws + base;
    short* Sb     = (short*)ar;
    short* VTbuf  = (short*)(ar + ((size_t)nb << 24));
    short* attedT = (short*)(ar + ((size_t)nb << 24) + ((size_t)nb << 23));
    short* Qb     = (short*)(ar + ((size_t)nb << 24) + ((size_t)nb << 23) + ((size_t)nb << 21));
    short* Kb     = (short*)(ar + ((size_t)nb << 24) + ((size_t)nb << 23) + 2 * ((size_t)nb << 21));
    short* Pd     = Kb;     // aliased: Kb dead after gemm1, Pd live softmax->gemm2

    hipLaunchKernelGGL(detect_kernel, dim3(1), dim3(64), 0, stream,
                       (const unsigned char*)mask, flags);
    hipLaunchKernelGGL(cvt_kernel, dim3(512), dim3(256), 0, stream,
                       Wm, Wb, (int)(DDIM * DDIM / 8));

    for (int c0 = 0; c0 < NBATCH; c0 += nb) {
        const float* vc = v + (size_t)c0 * LKS * DDIM;
        const float* kc = k + (size_t)c0 * LKS * DDIM;
        const float* qc = q + (size_t)c0 * LQS * DDIM;
        float*       oc = out + (size_t)c0 * DDIM * LQS;

        hipLaunchKernelGGL(cvt_kernel, dim3(1024), dim3(256), 0, stream,
                           qc, Qb, nb * (LQS * DDIM / 8));
        hipLaunchKernelGGL(cvt_kernel, dim3(2048), dim3(256), 0, stream,
                           kc, Kb, nb * (LKS * DDIM / 8));
        hipLaunchKernelGGL(transv_kernel, dim3(nb * 1024), dim3(256), 0, stream,
                           vc, VTbuf);
        hipLaunchKernelGGL(gemm1_kernel, dim3(nb * 64), dim3(512), 0, stream,
                           Qb, Kb, Sb);
        hipLaunchKernelGGL(softmax_kernel, dim3(nb * 1024), dim3(256), 0, stream,
                           Sb, Pd, mask, flags, c0);
        hipLaunchKernelGGL(gemm2_kernel, dim3(nb * 32), dim3(256), 0, stream,
                           VTbuf, Pd, attedT);
        hipLaunchKernelGGL(merge_kernel, dim3(nb * 32), dim3(256), 0, stream,
                           attedT, Wb, bias, oc);
    }
}

// Round 14
// 322.443 us; speedup vs baseline: 1.0540x; 1.0540x over previous
//
#include <hip/hip_runtime.h>
#include <stdint.h>

typedef __attribute__((ext_vector_type(4))) float f32x4;
typedef __attribute__((ext_vector_type(8))) short bf16x8;
typedef __attribute__((ext_vector_type(4))) short bf16x4v;
typedef __attribute__((ext_vector_type(4))) unsigned int u32x4;

#define NBATCH 8
#define LQS    1024
#define LKS    4096
#define DDIM   1024
#define QKSCALE 0.03125f
#define NEGINF -1000000000.0f
#define BK 64

__device__ __forceinline__ short f2bf(float x) {  // round-to-nearest-even
    unsigned u = __builtin_bit_cast(unsigned, x);
    unsigned r = (u + 0x7fffu + ((u >> 16) & 1u)) >> 16;
    return (short)r;
}
__device__ __forceinline__ float bf2f(short s) {
    unsigned u = ((unsigned)(unsigned short)s) << 16;
    return __builtin_bit_cast(float, u);
}

__device__ __forceinline__ bf16x8 cvt8(const float* f) {
    const u32x4* u = (const u32x4*)f;
    const u32x4 a = u[0], b = u[1];
    union { unsigned w[4]; bf16x8 v; } c;
    c.w[0] = __builtin_amdgcn_perm(a[1], a[0], 0x07060302u);
    c.w[1] = __builtin_amdgcn_perm(a[3], a[2], 0x07060302u);
    c.w[2] = __builtin_amdgcn_perm(b[1], b[0], 0x07060302u);
    c.w[3] = __builtin_amdgcn_perm(b[3], b[2], 0x07060302u);
    return c.v;
}

__device__ __forceinline__ void g2l16(const void* g, void* lds) {
    __builtin_amdgcn_global_load_lds(
        (const __attribute__((address_space(1))) unsigned int*)g,
        (__attribute__((address_space(3))) unsigned int*)lds,
        16, 0, 0);
}

// bijective XCD swizzle (all grids % 8 == 0)
__device__ __forceinline__ int xcd_swz(int bid, int nwg) {
    return (bid & 7) * (nwg >> 3) + (bid >> 3);
}

// ---- mask dtype detection ----
__global__ void detect_kernel(const unsigned char* __restrict__ mb,
                              int* __restrict__ flags) {
    if (threadIdx.x != 0 || blockIdx.x != 0) return;
    int is_i32 = 1;
    for (int i = 0; i < 256; ++i) {
        if ((i & 3) != 0 && mb[i] != 0) { is_i32 = 0; break; }
    }
    flags[0] = is_i32;
}

// ---- bulk fp32 -> bf16 ----
__global__ __launch_bounds__(256) void cvt_kernel(
    const float* __restrict__ src, short* __restrict__ dst, int n8) {
    const int stride = gridDim.x * 256;
    for (int i = blockIdx.x * 256 + threadIdx.x; i < n8; i += stride)
        ((bf16x8*)dst)[i] = cvt8(src + (size_t)i * 8);
}

// ---- transpose V[k][d] fp32 -> VT[d][k] bf16, 64x64 tiles ----
__global__ __launch_bounds__(256) void transv_kernel(
    const float* __restrict__ V, short* __restrict__ VT) {
    __shared__ short LDSt[64 * 72];
    const int tid = threadIdx.x;
    const int cb  = blockIdx.x >> 10;
    const int t   = blockIdx.x & 1023;
    const int kt  = t >> 4, dt = t & 15;
    const int k0  = kt * 64, d0 = dt * 64;
    const float* Vb  = V  + (size_t)cb * LKS * DDIM;
    short*       VTb = VT + (size_t)cb * ((size_t)DDIM * LKS);

    const int r  = tid >> 4;
    const int cp = (tid & 15) * 4;
#pragma unroll
    for (int rr = 0; rr < 4; ++rr) {
        const int row = rr * 16 + r;
        const f32x4 v = *(const f32x4*)(Vb + (size_t)(k0 + row) * DDIM + d0 + cp);
#pragma unroll
        for (int i = 0; i < 4; ++i) LDSt[(cp + i) * 72 + row] = f2bf(v[i]);
    }
    __syncthreads();
    const int dr = tid >> 2;
    const int kq = (tid & 3) * 16;
    const bf16x8 o0 = *(const bf16x8*)&LDSt[dr * 72 + kq];
    const bf16x8 o1 = *(const bf16x8*)&LDSt[dr * 72 + kq + 8];
    short* dst = VTb + (size_t)(d0 + dr) * LKS + k0 + kq;
    *(bf16x8*)dst       = o0;
    *(bf16x8*)(dst + 8) = o1;
}

// ============ shared staging / fragment helpers ============
__device__ __forceinline__ void stage_half(const short* gbase, int ld,
                                           short* ldshalf, int tid) {
    const int r0 = tid >> 3;
    const int gc = (tid & 7) ^ (r0 & 7);
    const short* s0 = gbase + (size_t)r0 * ld + gc * 8;
    const short* s1 = gbase + (size_t)(r0 + 64) * ld + gc * 8;
    g2l16(s0, ldshalf + (tid & 0x1C0) * 8);
    g2l16(s1, ldshalf + 4096 + (tid & 0x1C0) * 8);
}

__device__ __forceinline__ bf16x8 rdfrag(const short* lds, int base, int r, int c) {
    return *(const bf16x8*)&lds[base + r * 64 + ((c ^ (r & 7)) << 3)];
}

#define MFMA16(d, a, b) d = __builtin_amdgcn_mfma_f32_16x16x32_bf16(a, b, d, 0, 0, 0)

#define PHASE(MF0, STAGE, TAIL)                                             \
    {                                                                       \
        bf16x8 a00 = rdfrag(lds, aBase, (MF0) * 16 + lo, g);                \
        bf16x8 a01 = rdfrag(lds, aBase, (MF0) * 16 + lo, 4 + g);            \
        bf16x8 a10 = rdfrag(lds, aBase, (MF0) * 16 + 16 + lo, g);          \
        bf16x8 a11 = rdfrag(lds, aBase, (MF0) * 16 + 16 + lo, 4 + g);      \
        STAGE;                                                              \
        asm volatile("s_barrier" ::: "memory");                             \
        __builtin_amdgcn_s_setprio(1);                                      \
        _Pragma("unroll")                                                   \
        for (int nf = 0; nf < 4; ++nf) {                                    \
            MFMA16(acc[(MF0)][nf], a00, bfr[nf][0]);                        \
            MFMA16(acc[(MF0)][nf], a01, bfr[nf][1]);                        \
            MFMA16(acc[(MF0) + 1][nf], a10, bfr[nf][0]);                    \
            MFMA16(acc[(MF0) + 1][nf], a11, bfr[nf][1]);                    \
        }                                                                   \
        __builtin_amdgcn_s_setprio(0);                                      \
        TAIL;                                                               \
        asm volatile("s_barrier" ::: "memory");                             \
    }

// Epilogue store: EPI 0 = fp32*scale ; 1 = bf16 ; 2 = fp32+bias ; 3 = bf16*scale
// bf16 paths use an LDS-staged coalesced store (full-line segments; the direct
// bf16 store's 32B segments caused ~2x HBM write amplification - r11 counters).

// ============ 256x256 4-PHASE GEMM-BT (proven; tail-drain fixed in r10) ============
template <int EPI>
__device__ __forceinline__ void gemm8p_body(
    const short* __restrict__ A, int lda,
    const short* __restrict__ B, int ldb,
    void* __restrict__ C, int ldc,
    const float* __restrict__ bias,
    int m0, int n0, int NK, float scale, short* lds) {

    const int tid = threadIdx.x;
    const int w = tid >> 6, lane = tid & 63;
    const int lo = lane & 15, g = lane >> 4;
    const int wr = w >> 2, wc = w & 3;

    const short* gA0 = A + (size_t)m0 * lda;
    const short* gA1 = A + (size_t)(m0 + 128) * lda;
    const short* gB0 = B + (size_t)n0 * ldb;
    const short* gB1 = B + (size_t)(n0 + 128) * ldb;

    f32x4 acc[8][4];
#pragma unroll
    for (int mf = 0; mf < 8; ++mf)
#pragma unroll
        for (int nf = 0; nf < 4; ++nf) acc[mf][nf] = (f32x4){0.f, 0.f, 0.f, 0.f};

    stage_half(gA0, lda, lds + 0,     tid);
    stage_half(gA1, lda, lds + 8192,  tid);
    stage_half(gB0, ldb, lds + 16384, tid);
    stage_half(gB1, ldb, lds + 24576, tid);
    stage_half(gB0 + BK, ldb, lds + 32768 + 16384, tid);
    stage_half(gB1 + BK, ldb, lds + 32768 + 24576, tid);
    asm volatile("s_waitcnt vmcnt(4)" ::: "memory");
    asm volatile("s_barrier" ::: "memory");

    for (int kt = 0; kt < NK; ++kt) {
        const int cb = (kt & 1) << 15;
        const int ob = cb ^ 32768;
        const int aBase = cb + wr * 8192;
        const int bBase = cb + 16384 + (wc >> 1) * 8192;
        const int brow  = (wc & 1) * 64;
        const int kA = (kt + 1) * BK, kB = (kt + 2) * BK;
        const bool doA = (kt + 1) < NK, doB = (kt + 2) < NK;

        bf16x8 bfr[4][2];
#pragma unroll
        for (int nf = 0; nf < 4; ++nf) {
            bfr[nf][0] = rdfrag(lds, bBase, brow + nf * 16 + lo, g);
            bfr[nf][1] = rdfrag(lds, bBase, brow + nf * 16 + lo, 4 + g);
        }
        PHASE(0, if (doA) stage_half(gA0 + kA, lda, lds + ob, tid), )
        PHASE(2, if (doA) stage_half(gA1 + kA, lda, lds + ob + 8192, tid), )
        PHASE(4, if (doB) stage_half(gB0 + kB, ldb, lds + cb + 16384, tid), )
        PHASE(6, if (doB) stage_half(gB1 + kB, ldb, lds + cb + 24576, tid),
                 {
                     if (doB) { asm volatile("s_waitcnt vmcnt(4)" ::: "memory"); }
                     else     { asm volatile("s_waitcnt vmcnt(0)" ::: "memory"); }
                 })
    }

    if constexpr (EPI == 0 || EPI == 2) {
#pragma unroll
        for (int nf = 0; nf < 4; ++nf) {
            const int col = n0 + wc * 64 + nf * 16 + lo;
            float bv = 0.f;
            if constexpr (EPI == 2) bv = bias[col];
#pragma unroll
            for (int mf = 0; mf < 8; ++mf) {
#pragma unroll
                for (int rr = 0; rr < 4; ++rr) {
                    const size_t oa =
                        (size_t)(m0 + wr * 128 + mf * 16 + g * 4 + rr) * ldc + col;
                    if constexpr (EPI == 0) ((float*)C)[oa] = acc[mf][nf][rr] * scale;
                    else                    ((float*)C)[oa] = acc[mf][nf][rr] + bv;
                }
            }
        }
    } else {
        // bf16: LDS-coalesced, two half-passes over m (rows 0-127 = wr0, 128-255 = wr1)
        const float sc_ = (EPI == 3) ? scale : 1.f;
#pragma unroll
        for (int half = 0; half < 2; ++half) {
            if (wr == half) {
#pragma unroll
                for (int nf = 0; nf < 4; ++nf)
#pragma unroll
                    for (int mf = 0; mf < 8; ++mf)
#pragma unroll
                        for (int rr = 0; rr < 4; ++rr)
                            lds[(mf * 16 + g * 4 + rr) * 264 + wc * 64 + nf * 16 + lo] =
                                f2bf(acc[mf][nf][rr] * sc_);
            }
            __syncthreads();
#pragma unroll
            for (int it = 0; it < 8; ++it) {
                const int idx = it * 512 + tid;
                const int r_  = idx >> 5;
                const int c_  = (idx & 31) * 8;
                *(bf16x8*)((short*)C + (size_t)(m0 + half * 128 + r_) * ldc + n0 + c_) =
                    *(const bf16x8*)&lds[r_ * 264 + c_];
            }
            __syncthreads();
        }
    }
}

// ============ 256x128 2-PHASE variant, 512 thr / 8 waves (r12 best) ============
template <int EPI>
__device__ __forceinline__ void gemm8p_n128(
    const short* __restrict__ A, int lda,
    const short* __restrict__ B, int ldb,
    void* __restrict__ C, int ldc,
    const float* __restrict__ bias,
    int m0, int n0, int NK, float scale, short* lds) {

    const int tid = threadIdx.x;
    const int w = tid >> 6, lane = tid & 63;
    const int lo = lane & 15, g = lane >> 4;
    const int wr = w >> 1, wc = w & 1;

    const short* gA0 = A + (size_t)m0 * lda;
    const short* gA1 = A + (size_t)(m0 + 128) * lda;
    const short* gB0 = B + (size_t)n0 * ldb;

    f32x4 acc[4][4];
#pragma unroll
    for (int mf = 0; mf < 4; ++mf)
#pragma unroll
        for (int nf = 0; nf < 4; ++nf) acc[mf][nf] = (f32x4){0.f, 0.f, 0.f, 0.f};

    stage_half(gA0, lda, lds + 0,    tid);
    stage_half(gA1, lda, lds + 8192, tid);
    stage_half(gB0, ldb, lds + 16384, tid);
    stage_half(gB0 + BK, ldb, lds + 24576 + 16384, tid);
    asm volatile("s_waitcnt vmcnt(2)" ::: "memory");
    asm volatile("s_barrier" ::: "memory");

    for (int kt = 0; kt < NK; ++kt) {
        const int cbuf = (kt & 1) * 24576;
        const int obuf = cbuf ^ 24576;
        const int aBase = cbuf + (wr >> 1) * 8192 + (wr & 1) * 4096;
        const int bBase = cbuf + 16384 + wc * 4096;
        const int kA = (kt + 1) * BK, kB = (kt + 2) * BK;
        const bool doA = (kt + 1) < NK, doB = (kt + 2) < NK;

        bf16x8 bfr[4][2];
#pragma unroll
        for (int nf = 0; nf < 4; ++nf) {
            bfr[nf][0] = rdfrag(lds, bBase, nf * 16 + lo, g);
            bfr[nf][1] = rdfrag(lds, bBase, nf * 16 + lo, 4 + g);
        }
        PHASE(0, {
            if (doA) {
                stage_half(gA0 + kA, lda, lds + obuf, tid);
                stage_half(gA1 + kA, lda, lds + obuf + 8192, tid);
            }
        }, )
        PHASE(2, {
            if (doB) stage_half(gB0 + kB, ldb, lds + cbuf + 16384, tid);
        }, {
            if (doB) { asm volatile("s_waitcnt vmcnt(2)" ::: "memory"); }
            else     { asm volatile("s_waitcnt vmcnt(0)" ::: "memory"); }
        })
    }

    if constexpr (EPI == 0 || EPI == 2) {
#pragma unroll
        for (int nf = 0; nf < 4; ++nf) {
            const int col = n0 + wc * 64 + nf * 16 + lo;
            float bv = 0.f;
            if constexpr (EPI == 2) bv = bias[col];
#pragma unroll
            for (int mf = 0; mf < 4; ++mf) {
#pragma unroll
                for (int rr = 0; rr < 4; ++rr) {
                    const size_t oa =
                        (size_t)(m0 + wr * 64 + mf * 16 + g * 4 + rr) * ldc + col;
                    if constexpr (EPI == 0) ((float*)C)[oa] = acc[mf][nf][rr] * scale;
                    else                    ((float*)C)[oa] = acc[mf][nf][rr] + bv;
                }
            }
        }
    } else {
        // bf16: LDS-coalesced single pass, tile 256x128 in [256][136] shorts
        const float sc_ = (EPI == 3) ? scale : 1.f;
#pragma unroll
        for (int nf = 0; nf < 4; ++nf)
#pragma unroll
            for (int mf = 0; mf < 4; ++mf)
#pragma unroll
                for (int rr = 0; rr < 4; ++rr)
                    lds[(wr * 64 + mf * 16 + g * 4 + rr) * 136 + wc * 64 + nf * 16 + lo] =
                        f2bf(acc[mf][nf][rr] * sc_);
        __syncthreads();
#pragma unroll
        for (int it = 0; it < 8; ++it) {
            const int idx = it * 512 + tid;
            const int r_  = idx >> 4;
            const int c_  = (idx & 15) * 8;
            *(bf16x8*)((short*)C + (size_t)(m0 + r_) * ldc + n0 + c_) =
                *(const bf16x8*)&lds[r_ * 136 + c_];
        }
    }
}

// ---- gemm1: S[q][k] = bf16(scale * Qb·Kb^T) ; 256x256 tiles, grid nb*64 ----
__global__ __launch_bounds__(512, 2) void gemm1_kernel(
    const short* __restrict__ Qb, const short* __restrict__ Kb,
    short* __restrict__ Sb) {
    __shared__ __align__(16) short lds[65536];
    const int bid = xcd_swz(blockIdx.x, gridDim.x);
    const int cb = bid >> 6;
    const int t  = bid & 63;
    gemm8p_body<3>(Qb + (size_t)cb * LQS * DDIM, DDIM,
                   Kb + (size_t)cb * LKS * DDIM, DDIM,
                   Sb + (size_t)cb * ((size_t)LQS * LKS), LKS, nullptr,
                   (t >> 4) * 256, (t & 15) * 256, DDIM / BK, QKSCALE, lds);
}

// ---- gemm2: attedT[d][q] = VT·P^T ; 256x128 tiles, grid nb*32 (full chip) ----
__global__ __launch_bounds__(512, 2) void gemm2_kernel(
    const short* __restrict__ VT, const short* __restrict__ Pd,
    short* __restrict__ attedT) {
    __shared__ __align__(16) short lds[49152];
    const int bid = xcd_swz(blockIdx.x, gridDim.x);
    const int cb = bid >> 5;
    const int t  = bid & 31;
    gemm8p_n128<1>(VT + (size_t)cb * ((size_t)DDIM * LKS), LKS,
                   Pd + (size_t)cb * ((size_t)LQS * LKS), LKS,
                   attedT + (size_t)cb * ((size_t)DDIM * LQS), LQS, nullptr,
                   (t >> 3) * 256, (t & 7) * 128, LKS / BK, 1.f, lds);
}

// ---- merge: out[(b,d)][o] = attedT·Wb^T + bias ; 256x128, grid nb*32 ----
__global__ __launch_bounds__(512, 2) void merge_kernel(
    const short* __restrict__ attedT, const short* __restrict__ Wb,
    const float* __restrict__ bias, float* __restrict__ out) {
    __shared__ __align__(16) short lds[49152];
    const int bid = xcd_swz(blockIdx.x, gridDim.x);
    const int mt = bid >> 3;
    const int nt = bid & 7;
    gemm8p_n128<2>(attedT, DDIM, Wb, DDIM, out, DDIM, bias,
                   mt * 256, nt * 128, DDIM / BK, 1.f, lds);
}

// ---- softmax: one block per q-row; reads bf16 S, writes DENSE P bf16 ----
__global__ __launch_bounds__(256) void softmax_kernel(
    const short* __restrict__ Sb, short* __restrict__ Pd,
    const void* __restrict__ mask, const int* __restrict__ flags, int c0) {
    __shared__ float red[4];
    const int tid = threadIdx.x, w = tid >> 6, lane = tid & 63;
    const int cb = blockIdx.x >> 10;
    const int q  = blockIdx.x & 1023;
    const int mflag = flags[0];

    const short* Srow = Sb + ((size_t)cb * LQS + q) * LKS;
    const size_t roff = ((size_t)(c0 + cb) * LQS + q) * LKS;
    const size_t m4   = roff >> 2;   // int4 / uchar4 base index

    float sc[16];
#pragma unroll
    for (int j = 0; j < 2; ++j) {
        const int i8 = j * 256 + tid;
        const bf16x8 sv = ((const bf16x8*)Srow)[i8];
        int mm[8];
        if (mflag) {
            const int4 a = ((const int4*)mask)[m4 + 2 * i8];
            const int4 b = ((const int4*)mask)[m4 + 2 * i8 + 1];
            mm[0] = a.x; mm[1] = a.y; mm[2] = a.z; mm[3] = a.w;
            mm[4] = b.x; mm[5] = b.y; mm[6] = b.z; mm[7] = b.w;
        } else {
            const uchar4 a = ((const uchar4*)mask)[m4 + 2 * i8];
            const uchar4 b = ((const uchar4*)mask)[m4 + 2 * i8 + 1];
            mm[0] = a.x; mm[1] = a.y; mm[2] = a.z; mm[3] = a.w;
            mm[4] = b.x; mm[5] = b.y; mm[6] = b.z; mm[7] = b.w;
        }
#pragma unroll
        for (int i = 0; i < 8; ++i)
            sc[j * 8 + i] = mm[i] ? NEGINF : bf2f(sv[i]);
    }

    float lm = -INFINITY;
#pragma unroll
    for (int i = 0; i < 16; ++i) lm = fmaxf(lm, sc[i]);
#pragma unroll
    for (int off = 1; off < 64; off <<= 1) lm = fmaxf(lm, __shfl_xor(lm, off));
    if (lane == 0) red[w] = lm;
    __syncthreads();
    const float m = fmaxf(fmaxf(red[0], red[1]), fmaxf(red[2], red[3]));

    float p[16], ls = 0.f;
#pragma unroll
    for (int i = 0; i < 16; ++i) { p[i] = __expf(sc[i] - m); ls += p[i]; }
#pragma unroll
    for (int off = 1; off < 64; off <<= 1) ls += __shfl_xor(ls, off);
    __syncthreads();
    if (lane == 0) red[w] = ls;
    __syncthreads();
    const float inv = 1.f / (red[0] + red[1] + red[2] + red[3]);

    short* Prow = Pd + ((size_t)cb * LQS + q) * LKS;
#pragma unroll
    for (int j = 0; j < 2; ++j) {
        bf16x8 pv;
#pragma unroll
        for (int i = 0; i < 8; ++i) pv[i] = f2bf(p[j * 8 + i] * inv);
        ((bf16x8*)Prow)[j * 256 + tid] = pv;
    }
}

extern "C" void kernel_launch(void* const* d_in, const int* in_sizes, int n_in,
                              void* d_out, int out_size, void* d_ws, size_t ws_size,
                              hipStream_t stream) {
    // setup_inputs order: v, k, q, mask, W_merge, b_merge (fp32; mask i32/u8)
    const float* v    = (const float*)d_in[0];
    const float* k    = (const float*)d_in[1];
    const float* q    = (const float*)d_in[2];
    const void*  mask = d_in[3];
    const float* Wm   = (const float*)d_in[4];
    const float* bias = (const float*)d_in[5];
    float* out = (float*)d_out;

    const size_t base = 4096 + (2ull << 20);
    int nb = 0;
    for (int cand = 8; cand >= 1; cand >>= 1)
        if (base + (size_t)cand * (36ull << 20) <= ws_size) { nb = cand; break; }
    if (!nb) return;

    int*   flags = (int*)d_ws;
    short* Wb    = (short*)((char*)d_ws + 4096);
    char*  ar    = (char*)d_ws + base;
    short* Sb     = (short*)ar;
    short* VTbuf  = (short*)(ar + ((size_t)nb << 24));
    short* attedT = (short*)(ar + ((size_t)nb << 24) + ((size_t)nb << 23));
    short* Qb     = (short*)(ar + ((size_t)nb << 24) + ((size_t)nb << 23) + ((size_t)nb << 21));
    short* Kb     = (short*)(ar + ((size_t)nb << 24) + ((size_t)nb << 23) + 2 * ((size_t)nb << 21));
    short* Pd     = Kb;     // aliased: Kb dead after gemm1, Pd live softmax->gemm2

    hipLaunchKernelGGL(detect_kernel, dim3(1), dim3(64), 0, stream,
                       (const unsigned char*)mask, flags);
    hipLaunchKernelGGL(cvt_kernel, dim3(512), dim3(256), 0, stream,
                       Wm, Wb, (int)(DDIM * DDIM / 8));

    for (int c0 = 0; c0 < NBATCH; c0 += nb) {
        const float* vc = v + (size_t)c0 * LKS * DDIM;
        const float* kc = k + (size_t)c0 * LKS * DDIM;
        const float* qc = q + (size_t)c0 * LQS * DDIM;
        float*       oc = out + (size_t)c0 * DDIM * LQS;

        hipLaunchKernelGGL(cvt_kernel, dim3(1024), dim3(256), 0, stream,
                           qc, Qb, nb * (LQS * DDIM / 8));
        hipLaunchKernelGGL(cvt_kernel, dim3(2048), dim3(256), 0, stream,
                           kc, Kb, nb * (LKS * DDIM / 8));
        hipLaunchKernelGGL(transv_kernel, dim3(nb * 1024), dim3(256), 0, stream,
                           vc, VTbuf);
        hipLaunchKernelGGL(gemm1_kernel, dim3(nb * 64), dim3(512), 0, stream,
                           Qb, Kb, Sb);
        hipLaunchKernelGGL(softmax_kernel, dim3(nb * 1024), dim3(256), 0, stream,
                           Sb, Pd, mask, flags, c0);
        hipLaunchKernelGGL(gemm2_kernel, dim3(nb * 32), dim3(512), 0, stream,
                           VTbuf, Pd, attedT);
        hipLaunchKernelGGL(merge_kernel, dim3(nb * 32), dim3(512), 0, stream,
                           attedT, Wb, bias, oc);
    }
}

// Round 16
// 322.414 us; speedup vs baseline: 1.0541x; 1.0001x over previous
//
#include <hip/hip_runtime.h>
#include <stdint.h>

typedef __attribute__((ext_vector_type(4))) float f32x4;
typedef __attribute__((ext_vector_type(8))) short bf16x8;
typedef __attribute__((ext_vector_type(4))) short bf16x4v;
typedef __attribute__((ext_vector_type(4))) unsigned int u32x4;

#define NBATCH 8
#define LQS    1024
#define LKS    4096
#define DDIM   1024
#define QKSCALE 0.03125f
#define NEGINF -1000000000.0f
#define BK 64

__device__ __forceinline__ short f2bf(float x) {  // round-to-nearest-even
    unsigned u = __builtin_bit_cast(unsigned, x);
    unsigned r = (u + 0x7fffu + ((u >> 16) & 1u)) >> 16;
    return (short)r;
}
__device__ __forceinline__ float bf2f(short s) {
    unsigned u = ((unsigned)(unsigned short)s) << 16;
    return __builtin_bit_cast(float, u);
}

__device__ __forceinline__ bf16x8 cvt8(const float* f) {
    const u32x4* u = (const u32x4*)f;
    const u32x4 a = u[0], b = u[1];
    union { unsigned w[4]; bf16x8 v; } c;
    c.w[0] = __builtin_amdgcn_perm(a[1], a[0], 0x07060302u);
    c.w[1] = __builtin_amdgcn_perm(a[3], a[2], 0x07060302u);
    c.w[2] = __builtin_amdgcn_perm(b[1], b[0], 0x07060302u);
    c.w[3] = __builtin_amdgcn_perm(b[3], b[2], 0x07060302u);
    return c.v;
}

__device__ __forceinline__ void g2l16(const void* g, void* lds) {
    __builtin_amdgcn_global_load_lds(
        (const __attribute__((address_space(1))) unsigned int*)g,
        (__attribute__((address_space(3))) unsigned int*)lds,
        16, 0, 0);
}

// bijective XCD swizzle (all grids % 8 == 0)
__device__ __forceinline__ int xcd_swz(int bid, int nwg) {
    return (bid & 7) * (nwg >> 3) + (bid >> 3);
}

// ---- mask dtype detection ----
__global__ void detect_kernel(const unsigned char* __restrict__ mb,
                              int* __restrict__ flags) {
    if (threadIdx.x != 0 || blockIdx.x != 0) return;
    int is_i32 = 1;
    for (int i = 0; i < 256; ++i) {
        if ((i & 3) != 0 && mb[i] != 0) { is_i32 = 0; break; }
    }
    flags[0] = is_i32;
}

// ---- bulk fp32 -> bf16 ----
__global__ __launch_bounds__(256) void cvt_kernel(
    const float* __restrict__ src, short* __restrict__ dst, int n8) {
    const int stride = gridDim.x * 256;
    for (int i = blockIdx.x * 256 + threadIdx.x; i < n8; i += stride)
        ((bf16x8*)dst)[i] = cvt8(src + (size_t)i * 8);
}

// ---- transpose V[k][d] fp32 -> VT[d][k] bf16, 64x64 tiles ----
__global__ __launch_bounds__(256) void transv_kernel(
    const float* __restrict__ V, short* __restrict__ VT) {
    __shared__ short LDSt[64 * 72];
    const int tid = threadIdx.x;
    const int cb  = blockIdx.x >> 10;
    const int t   = blockIdx.x & 1023;
    const int kt  = t >> 4, dt = t & 15;
    const int k0  = kt * 64, d0 = dt * 64;
    const float* Vb  = V  + (size_t)cb * LKS * DDIM;
    short*       VTb = VT + (size_t)cb * ((size_t)DDIM * LKS);

    const int r  = tid >> 4;
    const int cp = (tid & 15) * 4;
#pragma unroll
    for (int rr = 0; rr < 4; ++rr) {
        const int row = rr * 16 + r;
        const f32x4 v = *(const f32x4*)(Vb + (size_t)(k0 + row) * DDIM + d0 + cp);
#pragma unroll
        for (int i = 0; i < 4; ++i) LDSt[(cp + i) * 72 + row] = f2bf(v[i]);
    }
    __syncthreads();
    const int dr = tid >> 2;
    const int kq = (tid & 3) * 16;
    const bf16x8 o0 = *(const bf16x8*)&LDSt[dr * 72 + kq];
    const bf16x8 o1 = *(const bf16x8*)&LDSt[dr * 72 + kq + 8];
    short* dst = VTb + (size_t)(d0 + dr) * LKS + k0 + kq;
    *(bf16x8*)dst       = o0;
    *(bf16x8*)(dst + 8) = o1;
}

// ============ shared staging / fragment helpers ============
__device__ __forceinline__ void stage_half(const short* gbase, int ld,
                                           short* ldshalf, int tid) {
    const int r0 = tid >> 3;
    const int gc = (tid & 7) ^ (r0 & 7);
    const short* s0 = gbase + (size_t)r0 * ld + gc * 8;
    const short* s1 = gbase + (size_t)(r0 + 64) * ld + gc * 8;
    g2l16(s0, ldshalf + (tid & 0x1C0) * 8);
    g2l16(s1, ldshalf + 4096 + (tid & 0x1C0) * 8);
}

__device__ __forceinline__ bf16x8 rdfrag(const short* lds, int base, int r, int c) {
    return *(const bf16x8*)&lds[base + r * 64 + ((c ^ (r & 7)) << 3)];
}

#define MFMA16(d, a, b) d = __builtin_amdgcn_mfma_f32_16x16x32_bf16(a, b, d, 0, 0, 0)

#define PHASE(MF0, STAGE, TAIL)                                             \
    {                                                                       \
        bf16x8 a00 = rdfrag(lds, aBase, (MF0) * 16 + lo, g);                \
        bf16x8 a01 = rdfrag(lds, aBase, (MF0) * 16 + lo, 4 + g);            \
        bf16x8 a10 = rdfrag(lds, aBase, (MF0) * 16 + 16 + lo, g);          \
        bf16x8 a11 = rdfrag(lds, aBase, (MF0) * 16 + 16 + lo, 4 + g);      \
        STAGE;                                                              \
        asm volatile("s_barrier" ::: "memory");                             \
        __builtin_amdgcn_s_setprio(1);                                      \
        _Pragma("unroll")                                                   \
        for (int nf = 0; nf < 4; ++nf) {                                    \
            MFMA16(acc[(MF0)][nf], a00, bfr[nf][0]);                        \
            MFMA16(acc[(MF0)][nf], a01, bfr[nf][1]);                        \
            MFMA16(acc[(MF0) + 1][nf], a10, bfr[nf][0]);                    \
            MFMA16(acc[(MF0) + 1][nf], a11, bfr[nf][1]);                    \
        }                                                                   \
        __builtin_amdgcn_s_setprio(0);                                      \
        TAIL;                                                               \
        asm volatile("s_barrier" ::: "memory");                             \
    }

// Epilogue store: EPI 0 = fp32*scale ; 1 = bf16 ; 2 = fp32+bias ; 3 = bf16*scale
// bf16 paths use an LDS-staged coalesced store (full-line segments; the direct
// bf16 store's 32B segments caused ~2x HBM write amplification - r11 counters).

// ============ 256x256 4-PHASE GEMM-BT (proven; tail-drain fixed in r10) ============
template <int EPI>
__device__ __forceinline__ void gemm8p_body(
    const short* __restrict__ A, int lda,
    const short* __restrict__ B, int ldb,
    void* __restrict__ C, int ldc,
    const float* __restrict__ bias,
    int m0, int n0, int NK, float scale, short* lds) {

    const int tid = threadIdx.x;
    const int w = tid >> 6, lane = tid & 63;
    const int lo = lane & 15, g = lane >> 4;
    const int wr = w >> 2, wc = w & 3;

    const short* gA0 = A + (size_t)m0 * lda;
    const short* gA1 = A + (size_t)(m0 + 128) * lda;
    const short* gB0 = B + (size_t)n0 * ldb;
    const short* gB1 = B + (size_t)(n0 + 128) * ldb;

    f32x4 acc[8][4];
#pragma unroll
    for (int mf = 0; mf < 8; ++mf)
#pragma unroll
        for (int nf = 0; nf < 4; ++nf) acc[mf][nf] = (f32x4){0.f, 0.f, 0.f, 0.f};

    stage_half(gA0, lda, lds + 0,     tid);
    stage_half(gA1, lda, lds + 8192,  tid);
    stage_half(gB0, ldb, lds + 16384, tid);
    stage_half(gB1, ldb, lds + 24576, tid);
    stage_half(gB0 + BK, ldb, lds + 32768 + 16384, tid);
    stage_half(gB1 + BK, ldb, lds + 32768 + 24576, tid);
    asm volatile("s_waitcnt vmcnt(4)" ::: "memory");
    asm volatile("s_barrier" ::: "memory");

    for (int kt = 0; kt < NK; ++kt) {
        const int cb = (kt & 1) << 15;
        const int ob = cb ^ 32768;
        const int aBase = cb + wr * 8192;
        const int bBase = cb + 16384 + (wc >> 1) * 8192;
        const int brow  = (wc & 1) * 64;
        const int kA = (kt + 1) * BK, kB = (kt + 2) * BK;
        const bool doA = (kt + 1) < NK, doB = (kt + 2) < NK;

        bf16x8 bfr[4][2];
#pragma unroll
        for (int nf = 0; nf < 4; ++nf) {
            bfr[nf][0] = rdfrag(lds, bBase, brow + nf * 16 + lo, g);
            bfr[nf][1] = rdfrag(lds, bBase, brow + nf * 16 + lo, 4 + g);
        }
        PHASE(0, if (doA) stage_half(gA0 + kA, lda, lds + ob, tid), )
        PHASE(2, if (doA) stage_half(gA1 + kA, lda, lds + ob + 8192, tid), )
        PHASE(4, if (doB) stage_half(gB0 + kB, ldb, lds + cb + 16384, tid), )
        PHASE(6, if (doB) stage_half(gB1 + kB, ldb, lds + cb + 24576, tid),
                 {
                     if (doB) { asm volatile("s_waitcnt vmcnt(4)" ::: "memory"); }
                     else     { asm volatile("s_waitcnt vmcnt(0)" ::: "memory"); }
                 })
    }

    if constexpr (EPI == 0 || EPI == 2) {
#pragma unroll
        for (int nf = 0; nf < 4; ++nf) {
            const int col = n0 + wc * 64 + nf * 16 + lo;
            float bv = 0.f;
            if constexpr (EPI == 2) bv = bias[col];
#pragma unroll
            for (int mf = 0; mf < 8; ++mf) {
#pragma unroll
                for (int rr = 0; rr < 4; ++rr) {
                    const size_t oa =
                        (size_t)(m0 + wr * 128 + mf * 16 + g * 4 + rr) * ldc + col;
                    if constexpr (EPI == 0) ((float*)C)[oa] = acc[mf][nf][rr] * scale;
                    else                    ((float*)C)[oa] = acc[mf][nf][rr] + bv;
                }
            }
        }
    } else {
        // bf16: LDS-coalesced, two half-passes over m (rows 0-127 = wr0, 128-255 = wr1)
        const float sc_ = (EPI == 3) ? scale : 1.f;
#pragma unroll
        for (int half = 0; half < 2; ++half) {
            if (wr == half) {
#pragma unroll
                for (int nf = 0; nf < 4; ++nf)
#pragma unroll
                    for (int mf = 0; mf < 8; ++mf)
#pragma unroll
                        for (int rr = 0; rr < 4; ++rr)
                            lds[(mf * 16 + g * 4 + rr) * 264 + wc * 64 + nf * 16 + lo] =
                                f2bf(acc[mf][nf][rr] * sc_);
            }
            __syncthreads();
#pragma unroll
            for (int it = 0; it < 8; ++it) {
                const int idx = it * 512 + tid;
                const int r_  = idx >> 5;
                const int c_  = (idx & 31) * 8;
                *(bf16x8*)((short*)C + (size_t)(m0 + half * 128 + r_) * ldc + n0 + c_) =
                    *(const bf16x8*)&lds[r_ * 264 + c_];
            }
            __syncthreads();
        }
    }
}

// ============ 256x128 2-PHASE variant, 512 thr / 8 waves (r12 best) ============
template <int EPI>
__device__ __forceinline__ void gemm8p_n128(
    const short* __restrict__ A, int lda,
    const short* __restrict__ B, int ldb,
    void* __restrict__ C, int ldc,
    const float* __restrict__ bias,
    int m0, int n0, int NK, float scale, short* lds) {

    const int tid = threadIdx.x;
    const int w = tid >> 6, lane = tid & 63;
    const int lo = lane & 15, g = lane >> 4;
    const int wr = w >> 1, wc = w & 1;

    const short* gA0 = A + (size_t)m0 * lda;
    const short* gA1 = A + (size_t)(m0 + 128) * lda;
    const short* gB0 = B + (size_t)n0 * ldb;

    f32x4 acc[4][4];
#pragma unroll
    for (int mf = 0; mf < 4; ++mf)
#pragma unroll
        for (int nf = 0; nf < 4; ++nf) acc[mf][nf] = (f32x4){0.f, 0.f, 0.f, 0.f};

    stage_half(gA0, lda, lds + 0,    tid);
    stage_half(gA1, lda, lds + 8192, tid);
    stage_half(gB0, ldb, lds + 16384, tid);
    stage_half(gB0 + BK, ldb, lds + 24576 + 16384, tid);
    asm volatile("s_waitcnt vmcnt(2)" ::: "memory");
    asm volatile("s_barrier" ::: "memory");

    for (int kt = 0; kt < NK; ++kt) {
        const int cbuf = (kt & 1) * 24576;
        const int obuf = cbuf ^ 24576;
        const int aBase = cbuf + (wr >> 1) * 8192 + (wr & 1) * 4096;
        const int bBase = cbuf + 16384 + wc * 4096;
        const int kA = (kt + 1) * BK, kB = (kt + 2) * BK;
        const bool doA = (kt + 1) < NK, doB = (kt + 2) < NK;

        bf16x8 bfr[4][2];
#pragma unroll
        for (int nf = 0; nf < 4; ++nf) {
            bfr[nf][0] = rdfrag(lds, bBase, nf * 16 + lo, g);
            bfr[nf][1] = rdfrag(lds, bBase, nf * 16 + lo, 4 + g);
        }
        PHASE(0, {
            if (doA) {
                stage_half(gA0 + kA, lda, lds + obuf, tid);
                stage_half(gA1 + kA, lda, lds + obuf + 8192, tid);
            }
        }, )
        PHASE(2, {
            if (doB) stage_half(gB0 + kB, ldb, lds + cbuf + 16384, tid);
        }, {
            if (doB) { asm volatile("s_waitcnt vmcnt(2)" ::: "memory"); }
            else     { asm volatile("s_waitcnt vmcnt(0)" ::: "memory"); }
        })
    }

    if constexpr (EPI == 0 || EPI == 2) {
#pragma unroll
        for (int nf = 0; nf < 4; ++nf) {
            const int col = n0 + wc * 64 + nf * 16 + lo;
            float bv = 0.f;
            if constexpr (EPI == 2) bv = bias[col];
#pragma unroll
            for (int mf = 0; mf < 4; ++mf) {
#pragma unroll
                for (int rr = 0; rr < 4; ++rr) {
                    const size_t oa =
                        (size_t)(m0 + wr * 64 + mf * 16 + g * 4 + rr) * ldc + col;
                    if constexpr (EPI == 0) ((float*)C)[oa] = acc[mf][nf][rr] * scale;
                    else                    ((float*)C)[oa] = acc[mf][nf][rr] + bv;
                }
            }
        }
    } else {
        // bf16: LDS-coalesced single pass, tile 256x128 in [256][136] shorts
        const float sc_ = (EPI == 3) ? scale : 1.f;
#pragma unroll
        for (int nf = 0; nf < 4; ++nf)
#pragma unroll
            for (int mf = 0; mf < 4; ++mf)
#pragma unroll
                for (int rr = 0; rr < 4; ++rr)
                    lds[(wr * 64 + mf * 16 + g * 4 + rr) * 136 + wc * 64 + nf * 16 + lo] =
                        f2bf(acc[mf][nf][rr] * sc_);
        __syncthreads();
#pragma unroll
        for (int it = 0; it < 8; ++it) {
            const int idx = it * 512 + tid;
            const int r_  = idx >> 4;
            const int c_  = (idx & 15) * 8;
            *(bf16x8*)((short*)C + (size_t)(m0 + r_) * ldc + n0 + c_) =
                *(const bf16x8*)&lds[r_ * 136 + c_];
        }
    }
}

// ---- gemm1: S[q][k] = bf16(scale * Qb·Kb^T) ; 256x256 tiles, grid nb*64 ----
__global__ __launch_bounds__(512, 2) void gemm1_kernel(
    const short* __restrict__ Qb, const short* __restrict__ Kb,
    short* __restrict__ Sb) {
    __shared__ __align__(16) short lds[65536];
    const int bid = xcd_swz(blockIdx.x, gridDim.x);
    const int cb = bid >> 6;
    const int t  = bid & 63;
    gemm8p_body<3>(Qb + (size_t)cb * LQS * DDIM, DDIM,
                   Kb + (size_t)cb * LKS * DDIM, DDIM,
                   Sb + (size_t)cb * ((size_t)LQS * LKS), LKS, nullptr,
                   (t >> 4) * 256, (t & 15) * 256, DDIM / BK, QKSCALE, lds);
}

// ---- gemm2: attedT[d][q] = VT·P^T ; 256x128 tiles, grid nb*32 (full chip) ----
__global__ __launch_bounds__(512, 2) void gemm2_kernel(
    const short* __restrict__ VT, const short* __restrict__ Pd,
    short* __restrict__ attedT) {
    __shared__ __align__(16) short lds[49152];
    const int bid = xcd_swz(blockIdx.x, gridDim.x);
    const int cb = bid >> 5;
    const int t  = bid & 31;
    gemm8p_n128<1>(VT + (size_t)cb * ((size_t)DDIM * LKS), LKS,
                   Pd + (size_t)cb * ((size_t)LQS * LKS), LKS,
                   attedT + (size_t)cb * ((size_t)DDIM * LQS), LQS, nullptr,
                   (t >> 3) * 256, (t & 7) * 128, LKS / BK, 1.f, lds);
}

// ---- merge: out[(b,d)][o] = attedT·Wb^T + bias ; 256x128, grid nb*32 ----
__global__ __launch_bounds__(512, 2) void merge_kernel(
    const short* __restrict__ attedT, const short* __restrict__ Wb,
    const float* __restrict__ bias, float* __restrict__ out) {
    __shared__ __align__(16) short lds[49152];
    const int bid = xcd_swz(blockIdx.x, gridDim.x);
    const int mt = bid >> 3;
    const int nt = bid & 7;
    gemm8p_n128<2>(attedT, DDIM, Wb, DDIM, out, DDIM, bias,
                   mt * 256, nt * 128, DDIM / BK, 1.f, lds);
}

// ---- softmax: one block per q-row; reads bf16 S, writes DENSE P bf16 ----
__global__ __launch_bounds__(256) void softmax_kernel(
    const short* __restrict__ Sb, short* __restrict__ Pd,
    const void* __restrict__ mask, const int* __restrict__ flags, int c0) {
    __shared__ float red[4];
    const int tid = threadIdx.x, w = tid >> 6, lane = tid & 63;
    const int cb = blockIdx.x >> 10;
    const int q  = blockIdx.x & 1023;
    const int mflag = flags[0];

    const short* Srow = Sb + ((size_t)cb * LQS + q) * LKS;
    const size_t roff = ((size_t)(c0 + cb) * LQS + q) * LKS;
    const size_t m4   = roff >> 2;   // int4 / uchar4 base index

    float sc[16];
#pragma unroll
    for (int j = 0; j < 2; ++j) {
        const int i8 = j * 256 + tid;
        const bf16x8 sv = ((const bf16x8*)Srow)[i8];
        int mm[8];
        if (mflag) {
            const int4 a = ((const int4*)mask)[m4 + 2 * i8];
            const int4 b = ((const int4*)mask)[m4 + 2 * i8 + 1];
            mm[0] = a.x; mm[1] = a.y; mm[2] = a.z; mm[3] = a.w;
            mm[4] = b.x; mm[5] = b.y; mm[6] = b.z; mm[7] = b.w;
        } else {
            const uchar4 a = ((const uchar4*)mask)[m4 + 2 * i8];
            const uchar4 b = ((const uchar4*)mask)[m4 + 2 * i8 + 1];
            mm[0] = a.x; mm[1] = a.y; mm[2] = a.z; mm[3] = a.w;
            mm[4] = b.x; mm[5] = b.y; mm[6] = b.z; mm[7] = b.w;
        }
#pragma unroll
        for (int i = 0; i < 8; ++i)
            sc[j * 8 + i] = mm[i] ? NEGINF : bf2f(sv[i]);
    }

    float lm = -INFINITY;
#pragma unroll
    for (int i = 0; i < 16; ++i) lm = fmaxf(lm, sc[i]);
#pragma unroll
    for (int off = 1; off < 64; off <<= 1) lm = fmaxf(lm, __shfl_xor(lm, off));
    if (lane == 0) red[w] = lm;
    __syncthreads();
    const float m = fmaxf(fmaxf(red[0], red[1]), fmaxf(red[2], red[3]));

    float p[16], ls = 0.f;
#pragma unroll
    for (int i = 0; i < 16; ++i) { p[i] = __expf(sc[i] - m); ls += p[i]; }
#pragma unroll
    for (int off = 1; off < 64; off <<= 1) ls += __shfl_xor(ls, off);
    __syncthreads();
    if (lane == 0) red[w] = ls;
    __syncthreads();
    const float inv = 1.f / (red[0] + red[1] + red[2] + red[3]);

    short* Prow = Pd + ((size_t)cb * LQS + q) * LKS;
#pragma unroll
    for (int j = 0; j < 2; ++j) {
        bf16x8 pv;
#pragma unroll
        for (int i = 0; i < 8; ++i) pv[i] = f2bf(p[j * 8 + i] * inv);
        ((bf16x8*)Prow)[j * 256 + tid] = pv;
    }
}

extern "C" void kernel_launch(void* const* d_in, const int* in_sizes, int n_in,
                              void* d_out, int out_size, void* d_ws, size_t ws_size,
                              hipStream_t stream) {
    // setup_inputs order: v, k, q, mask, W_merge, b_merge (fp32; mask i32/u8)
    const float* v    = (const float*)d_in[0];
    const float* k    = (const float*)d_in[1];
    const float* q    = (const float*)d_in[2];
    const void*  mask = d_in[3];
    const float* Wm   = (const float*)d_in[4];
    const float* bias = (const float*)d_in[5];
    float* out = (float*)d_out;

    const size_t base = 4096 + (2ull << 20);
    int nb = 0;
    for (int cand = 8; cand >= 1; cand >>= 1)
        if (base + (size_t)cand * (36ull << 20) <= ws_size) { nb = cand; break; }
    if (!nb) return;

    int*   flags = (int*)d_ws;
    short* Wb    = (short*)((char*)d_ws + 4096);
    char*  ar    = (char*)d_ws + base;
    short* Sb     = (short*)ar;
    short* VTbuf  = (short*)(ar + ((size_t)nb << 24));
    short* attedT = (short*)(ar + ((size_t)nb << 24) + ((size_t)nb << 23));
    short* Qb     = (short*)(ar + ((size_t)nb << 24) + ((size_t)nb << 23) + ((size_t)nb << 21));
    short* Kb     = (short*)(ar + ((size_t)nb << 24) + ((size_t)nb << 23) + 2 * ((size_t)nb << 21));
    short* Pd     = Kb;     // aliased: Kb dead after gemm1, Pd live softmax->gemm2

    hipLaunchKernelGGL(detect_kernel, dim3(1), dim3(64), 0, stream,
                       (const unsigned char*)mask, flags);
    hipLaunchKernelGGL(cvt_kernel, dim3(512), dim3(256), 0, stream,
                       Wm, Wb, (int)(DDIM * DDIM / 8));

    for (int c0 = 0; c0 < NBATCH; c0 += nb) {
        const float* vc = v + (size_t)c0 * LKS * DDIM;
        const float* kc = k + (size_t)c0 * LKS * DDIM;
        const float* qc = q + (size_t)c0 * LQS * DDIM;
        float*       oc = out + (size_t)c0 * DDIM * LQS;

        hipLaunchKernelGGL(cvt_kernel, dim3(1024), dim3(256), 0, stream,
                           qc, Qb, nb * (LQS * DDIM / 8));
        hipLaunchKernelGGL(cvt_kernel, dim3(2048), dim3(256), 0, stream,
                           kc, Kb, nb * (LKS * DDIM / 8));
        hipLaunchKernelGGL(transv_kernel, dim3(nb * 1024), dim3(256), 0, stream,
                           vc, VTbuf);
        hipLaunchKernelGGL(gemm1_kernel, dim3(nb * 64), dim3(512), 0, stream,
                           Qb, Kb, Sb);
        hipLaunchKernelGGL(softmax_kernel, dim3(nb * 1024), dim3(256), 0, stream,
                           Sb, Pd, mask, flags, c0);
        hipLaunchKernelGGL(gemm2_kernel, dim3(nb * 32), dim3(512), 0, stream,
                           VTbuf, Pd, attedT);
        hipLaunchKernelGGL(merge_kernel, dim3(nb * 32), dim3(512), 0, stream,
                           attedT, Wb, bias, oc);
    }
}